// Round 10
// baseline (91.460 us; speedup 1.0000x reference)
//
#include <hip/hip_runtime.h>
#include <cstdint>
#include <math.h>

#define B_ROWS 4096
#define HALF_B 2048
#define NT_COLS 8192
#define P_POS 8
#define K_NEG 1016
#define N_PAD 3079.0f          // B - (1+K)
#define A_C 1.57694f
#define BB_C 0.89506f
#define INV_T 6.66666666667f
#define THREADS 1024
#define EPT 8                  // NT_COLS / THREADS
#define LN2_F 0.69314718056f
#define INV_LN2_F 1.44269504089f
#define NBINS 2048
#define CMAX 128

__device__ __forceinline__ float hw_log2(float x) { return __builtin_amdgcn_logf(x); }
__device__ __forceinline__ float hw_exp2(float x) { return __builtin_amdgcn_exp2f(x); }

// 1-instruction rotate on device (v_alignbit_b32), plain on host
__host__ __device__ __forceinline__ uint32_t rotl32(uint32_t x, int r) {
#ifdef __HIP_DEVICE_COMPILE__
  return __builtin_amdgcn_alignbit(x, x, (uint32_t)(32 - r));
#else
  return (x << r) | (x >> (32 - r));
#endif
}

// ---- Threefry-2x32, 20 rounds, exactly JAX's schedule ----
__host__ __device__ __forceinline__ void tf2x32(uint32_t k0, uint32_t k1,
                                                uint32_t& x0, uint32_t& x1) {
  const uint32_t ks2 = k0 ^ k1 ^ 0x1BD11BDAu;
  x0 += k0; x1 += k1;
#define TF_RND(r) { x0 += x1; x1 = rotl32(x1, r); x1 ^= x0; }
  TF_RND(13) TF_RND(15) TF_RND(26) TF_RND(6)
  x0 += k1;  x1 += ks2 + 1u;
  TF_RND(17) TF_RND(29) TF_RND(16) TF_RND(24)
  x0 += ks2; x1 += k0 + 2u;
  TF_RND(13) TF_RND(15) TF_RND(26) TF_RND(6)
  x0 += k0;  x1 += k1 + 3u;
  TF_RND(17) TF_RND(29) TF_RND(16) TF_RND(24)
  x0 += k1;  x1 += ks2 + 4u;
  TF_RND(13) TF_RND(15) TF_RND(26) TF_RND(6)
  x0 += ks2; x1 += k0 + 5u;
#undef TF_RND
}

__device__ __forceinline__ float sim_fast(float x0, float x1, float xsq,
                                          float tx, float ty) {
  float tsq = tx * tx + ty * ty;
  float d2 = fmaxf(xsq + tsq - 2.0f * (x0 * tx + x1 * ty), 1e-12f);
  return 1.0f / (1.0f + A_C * hw_exp2(BB_C * hw_log2(d2)));
}

// t = (-ln u) * wf^-0.75 = exp(-score): rank DESC by score == rank ASC by t.
// u==0 (prob 2^-23) -> t=+inf -> lowest priority (JAX's clamp likewise never
// selects it). Flip bits so "select K largest keys" machinery is unchanged.
__device__ __forceinline__ uint32_t make_key(uint32_t bits, float w75n) {
  float f = __uint_as_float((bits >> 9) | 0x3f800000u) - 1.0f;   // u in [0,1)
  float t = hw_log2(f) * w75n;                                   // >0 (w75n<0)
  return ~__float_as_uint(t);
}

__global__ void prew_kernel(const float* __restrict__ wf,
                            float* __restrict__ w75n) {
  int i = blockIdx.x * 256 + threadIdx.x;
  if (i < NT_COLS) w75n[i] = -powf(wf[i], -0.75f);
}

// post-histogram scan + boundary find for one 11-bit digit at SHIFT.
// hist is PACKED: row A counts in low 16 bits, row B in high 16 bits.
template <int SHIFT>
__device__ __forceinline__ void scan_pass(
    uint32_t* hist, bool rezero,
    uint32_t& prefA, uint32_t& remA, uint32_t& prefB, uint32_t& remB,
    uint32_t* wsum, volatile uint32_t* sh_scal, int tid, int lane, int wv) {
  __syncthreads();
  uint2 av = ((uint2*)hist)[tid];               // bins 2tid, 2tid+1 (packed)
  if (rezero) ((uint2*)hist)[tid] = make_uint2(0u, 0u);
  uint32_t P = av.x + av.y;                     // packed pair total
  uint32_t ia = P;
#pragma unroll
  for (int off = 1; off < 64; off <<= 1) {      // packed in-wave suffix scan
    uint32_t u = __shfl_down(ia, off);
    if (lane + off < 64) ia += u;
  }
  if (lane == 0) wsum[wv] = ia;
  __syncthreads();
  uint32_t t = wsum[lane & 15], o = t;
#pragma unroll
  for (int off = 1; off < 16; off <<= 1) {      // packed wave-total suffix
    uint32_t u = __shfl_down(t, off);
    if (lane + off < 16) t += u;
  }
  uint32_t e = (uint32_t)__builtin_amdgcn_readlane((int)(t - o), wv);
  uint32_t S = e + (ia - P);                    // packed strictly-after sum
  uint32_t SA = S & 0xFFFFu, SB = S >> 16;
  uint32_t a0A = av.x & 0xFFFFu, a0B = av.x >> 16;
  uint32_t a1A = av.y & 0xFFFFu, a1B = av.y >> 16;
  {
    uint32_t gt1 = SA, ge1 = a1A + SA, gt0 = ge1, ge0 = a0A + ge1;
    if (ge0 >= remA && gt0 < remA) { sh_scal[0] = prefA | ((uint32_t)(2 * tid) << SHIFT); sh_scal[1] = remA - gt0; }
    if (ge1 >= remA && gt1 < remA) { sh_scal[0] = prefA | ((uint32_t)(2 * tid + 1) << SHIFT); sh_scal[1] = remA - gt1; }
  }
  {
    uint32_t gt1 = SB, ge1 = a1B + SB, gt0 = ge1, ge0 = a0B + ge1;
    if (ge0 >= remB && gt0 < remB) { sh_scal[2] = prefB | ((uint32_t)(2 * tid) << SHIFT); sh_scal[3] = remB - gt0; }
    if (ge1 >= remB && gt1 < remB) { sh_scal[2] = prefB | ((uint32_t)(2 * tid + 1) << SHIFT); sh_scal[3] = remB - gt1; }
  }
  __syncthreads();
  prefA = sh_scal[0]; remA = sh_scal[1];
  prefB = sh_scal[2]; remB = sh_scal[3];
}

__global__ __launch_bounds__(THREADS, 8) void cdr_pair_kernel(
    const float* __restrict__ x_emb, const float* __restrict__ t_emb,
    const float* __restrict__ w75n, const float* __restrict__ wf,
    const int* __restrict__ pos_idx,
    float* __restrict__ row_loss, float* __restrict__ out_atomic,
    uint32_t fk0, uint32_t fk1) {
  __shared__ uint32_t hist[NBINS];      // 8 KB, packed A|B
  __shared__ uint32_t candK[2][CMAX];   // 1 KB
  __shared__ uint16_t candC[2][CMAX];   // 0.5 KB
  __shared__ uint32_t wsum[16];
  __shared__ uint32_t sh_scal[4];
  __shared__ uint32_t sh_cnt[2], sh_tie[2];
  __shared__ uint32_t sh_theta[2], sh_need[2];
  __shared__ int sh_pos[2 * P_POS];
  __shared__ float shA[16], shB[16], sh_pp[16];

  const int r0 = blockIdx.x;            // 0..2047
  const int r1 = r0 + HALF_B;
  const int tid = threadIdx.x;
  const int lane = tid & 63;
  const int wv = tid >> 6;

  ((uint2*)hist)[tid] = make_uint2(0u, 0u);
  if (tid < P_POS) sh_pos[tid] = pos_idx[r0 * P_POS + tid];
  else if (tid < 2 * P_POS) sh_pos[tid] = pos_idx[r1 * P_POS + (tid - P_POS)];
  if (tid < 2) { sh_cnt[tid] = 0u; sh_tie[tid] = 0u; }
  __syncthreads();

  // consecutive-cols layout: this thread owns cols [tid*8, tid*8+8)
  const int colbase = tid * EPT;
  uint32_t m0 = 0u, m1 = 0u;
#pragma unroll
  for (int p = 0; p < P_POS; ++p) {
    int c0 = sh_pos[p], c1 = sh_pos[P_POS + p];
    if ((c0 >> 3) == tid) m0 |= 1u << (c0 & 7);
    if ((c1 >> 3) == tid) m1 |= 1u << (c1 & 7);
  }

  float wv8[EPT];
  if (w75n) {
    const float4* w4 = (const float4*)w75n;
    float4 wA = w4[2 * tid], wB = w4[2 * tid + 1];
    wv8[0] = wA.x; wv8[1] = wA.y; wv8[2] = wA.z; wv8[3] = wA.w;
    wv8[4] = wB.x; wv8[5] = wB.y; wv8[6] = wB.z; wv8[7] = wB.w;
  } else {
#pragma unroll
    for (int i = 0; i < EPT; ++i)
      wv8[i] = -hw_exp2(-0.75f * hw_log2(wf[colbase + i]));
  }

  // ---- phase 1: threefry -> keys (regs) with FUSED pass-1 histogram ----
  uint32_t k0[EPT], k1[EPT];
  const uint32_t H = 16777216u;   // (B*NT)/2
  const uint32_t nbase = (uint32_t)(r0 * NT_COLS + colbase);
#pragma unroll
  for (int i = 0; i < EPT; ++i) {
    uint32_t xa = nbase + (uint32_t)i, xb = xa + H;
    tf2x32(fk0, fk1, xa, xb);
    uint32_t ka = make_key(xa, wv8[i]);
    uint32_t kb = make_key(xb, wv8[i]);
    ka = ((m0 >> i) & 1u) ? 0u : ka;
    kb = ((m1 >> i) & 1u) ? 0u : kb;
    k0[i] = ka; k1[i] = kb;
    atomicAdd(&hist[ka >> 21], 1u);          // row A: low 16 bits
    atomicAdd(&hist[kb >> 21], 0x10000u);    // row B: high 16 bits
  }

  // ---- phase 2: digit 1 scan, then guarded digit 2 ----
  uint32_t prefA = 0u, prefB = 0u, remA = K_NEG, remB = K_NEG;
  scan_pass<21>(hist, true, prefA, remA, prefB, remB,
                wsum, sh_scal, tid, lane, wv);
  const uint32_t PM11 = 0xFFE00000u;
#pragma unroll
  for (int i = 0; i < EPT; ++i) {
    uint32_t ka = k0[i];
    if ((ka & PM11) == prefA) atomicAdd(&hist[(ka >> 10) & 0x7FFu], 1u);
    uint32_t kb = k1[i];
    if ((kb & PM11) == prefB) atomicAdd(&hist[(kb >> 10) & 0x7FFu], 0x10000u);
  }
  scan_pass<10>(hist, false, prefA, remA, prefB, remB,
                wsum, sh_scal, tid, lane, wv);
  const uint32_t PM22 = 0xFFFFFC00u;

  const float xa0 = x_emb[r0 * 2], xa1 = x_emb[r0 * 2 + 1];
  const float xb0 = x_emb[r1 * 2], xb1 = x_emb[r1 * 2 + 1];
  const float qa = xa0 * xa0 + xa1 * xa1;
  const float qb = xb0 * xb0 + xb1 * xb1;
  const float2* temb2 = (const float2*)t_emb;

  // ---- phase 3: direct accumulation of definitely-selected negatives;
  //      prefix-tied keys go to the tiny candidate buffer ----
  float accA = 0.0f, accB = 0.0f;
#pragma unroll
  for (int i = 0; i < EPT; ++i) {
    const int col = colbase + i;
    float2 t = temb2[col];
    {
      uint32_t k = k0[i];
      uint32_t p22 = k & PM22;
      if (p22 > prefA) {
        float s = sim_fast(xa0, xa1, qa, t.x, t.y);
        accA += hw_exp2(s * (INV_T * INV_LN2_F));
      } else if (p22 == prefA) {
        uint32_t s = atomicAdd(&sh_cnt[0], 1u);
        if (s < CMAX) { candK[0][s] = k; candC[0][s] = (uint16_t)col; }
      }
    }
    {
      uint32_t k = k1[i];
      uint32_t p22 = k & PM22;
      if (p22 > prefB) {
        float s = sim_fast(xb0, xb1, qb, t.x, t.y);
        accB += hw_exp2(s * (INV_T * INV_LN2_F));
      } else if (p22 == prefB) {
        uint32_t s = atomicAdd(&sh_cnt[1], 1u);
        if (s < CMAX) { candK[1][s] = k; candC[1][s] = (uint16_t)col; }
      }
    }
  }
  __syncthreads();

  // ---- phase 3b: resolve exact theta among the prefix-tied candidates ----
  if (tid < 2) {
    uint32_t c = sh_cnt[tid]; if (c > CMAX) c = CMAX;
    uint32_t rr = tid ? remB : remA;
    uint32_t th = 0u, nd = 0u;
    for (uint32_t j = 0; j < c; ++j) {
      uint32_t kj = candK[tid][j];
      uint32_t gt = 0u, eq = 0u;
      for (uint32_t l = 0; l < c; ++l) { gt += (candK[tid][l] > kj); eq += (candK[tid][l] == kj); }
      if (gt < rr && gt + eq >= rr) { th = kj; nd = rr - gt; }
    }
    sh_theta[tid] = th; sh_need[tid] = nd;
  }
  __syncthreads();

  // ---- phase 3c: boundary candidates accumulate too ----
  if (tid < 2 * CMAX) {
    const int rsb = tid >> 7;
    const uint32_t j = tid & (CMAX - 1);
    uint32_t c = sh_cnt[rsb]; if (c > CMAX) c = CMAX;
    if (j < c) {
      uint32_t k = candK[rsb][j];
      uint32_t th = sh_theta[rsb];
      bool inc = (k > th);
      if (k == th) inc = (atomicAdd(&sh_tie[rsb], 1u) < sh_need[rsb]);
      if (inc) {
        int col = candC[rsb][j];
        float2 t = temb2[col];
        if (rsb) {
          float s = sim_fast(xb0, xb1, qb, t.x, t.y);
          accB += hw_exp2(s * (INV_T * INV_LN2_F));
        } else {
          float s = sim_fast(xa0, xa1, qa, t.x, t.y);
          accA += hw_exp2(s * (INV_T * INV_LN2_F));
        }
      }
    }
  }

  // ---- phase 4: block reduce + positives + loss ----
#pragma unroll
  for (int off = 32; off > 0; off >>= 1) {
    accA += __shfl_down(accA, off);
    accB += __shfl_down(accB, off);
  }
  if (lane == 0) { shA[wv] = accA; shB[wv] = accB; }
  if (tid < 16) {
    int rowb = tid >> 3;
    int c = sh_pos[tid];
    float2 t = temb2[c];
    float px = rowb ? xb0 : xa0;
    float py = rowb ? xb1 : xa1;
    float pq = rowb ? qb : qa;
    sh_pp[tid] = sim_fast(px, py, pq, t.x, t.y);
  }
  __syncthreads();

  if (tid < 2) {
    float s = 0.0f;
#pragma unroll
    for (int w = 0; w < 16; ++w) s += tid ? shB[w] : shA[w];
    float ps = 0.0f;
#pragma unroll
    for (int p = 0; p < P_POS; ++p) ps += sh_pp[tid * P_POS + p];
    float pos = ps * (1.0f / P_POS);
    float zpos = pos * INV_T;
    float S = s + hw_exp2(zpos * INV_LN2_F) + N_PAD;
    float loss = logf(S) - zpos;
    int r = tid ? r1 : r0;
    if (row_loss) row_loss[r] = loss;
    else atomicAdd(out_atomic, loss * (1.0f / B_ROWS));
  }
}

__global__ __launch_bounds__(256) void cdr_reduce_kernel(
    const float* __restrict__ row_loss, float* __restrict__ out) {
  __shared__ float part[4];
  float s = 0.0f;
  for (int i = threadIdx.x; i < B_ROWS; i += 256) s += row_loss[i];
#pragma unroll
  for (int off = 32; off > 0; off >>= 1) s += __shfl_down(s, off);
  if ((threadIdx.x & 63) == 0) part[threadIdx.x >> 6] = s;
  __syncthreads();
  if (threadIdx.x == 0)
    out[0] = (part[0] + part[1] + part[2] + part[3]) * (1.0f / B_ROWS);
}

__global__ void cdr_zero_kernel(float* __restrict__ out) { out[0] = 0.0f; }

extern "C" void kernel_launch(void* const* d_in, const int* in_sizes, int n_in,
                              void* d_out, int out_size, void* d_ws, size_t ws_size,
                              hipStream_t stream) {
  const float* x_emb = (const float*)d_in[0];
  const float* t_emb = (const float*)d_in[1];
  const float* wf    = (const float*)d_in[2];
  const int*   pidx  = (const int*)d_in[3];
  float* out = (float*)d_out;

  uint32_t fk0 = 0u, fk1 = 1u;
  tf2x32(0u, 0u, fk0, fk1);

  const bool has_w75 = (ws_size >= (size_t)(NT_COLS + B_ROWS) * sizeof(float));
  const bool has_rl  = (ws_size >= (size_t)B_ROWS * sizeof(float));

  float* w75n = nullptr;
  float* row_loss = nullptr;
  if (has_w75) { w75n = (float*)d_ws; row_loss = (float*)d_ws + NT_COLS; }
  else if (has_rl) { row_loss = (float*)d_ws; }

  if (has_w75) {
    hipLaunchKernelGGL(prew_kernel, dim3(NT_COLS / 256), dim3(256), 0, stream,
                       wf, w75n);
  }
  if (!row_loss) {
    hipLaunchKernelGGL(cdr_zero_kernel, dim3(1), dim3(1), 0, stream, out);
  }
  hipLaunchKernelGGL(cdr_pair_kernel, dim3(HALF_B), dim3(THREADS), 0, stream,
                     x_emb, t_emb, w75n, wf, pidx, row_loss, out, fk0, fk1);
  if (row_loss) {
    hipLaunchKernelGGL(cdr_reduce_kernel, dim3(1), dim3(256), 0, stream,
                       row_loss, out);
  }
}

// Round 11
// 81.788 us; speedup vs baseline: 1.1183x; 1.1183x over previous
//
#include <hip/hip_runtime.h>
#include <cstdint>
#include <math.h>

#define B_ROWS 4096
#define HALF_B 2048
#define NT_COLS 8192
#define P_POS 8
#define K_NEG 1016
#define N_PAD 3079.0f          // B - (1+K)
#define A_C 1.57694f
#define BB_C 0.89506f
#define INV_T 6.66666666667f
#define THREADS 1024
#define EPT 8                  // NT_COLS / THREADS
#define LN2_F 0.69314718056f
#define INV_LN2_F 1.44269504089f
#define NBINS 2048
#define CMAX 128

__device__ __forceinline__ float hw_log2(float x) { return __builtin_amdgcn_logf(x); }
__device__ __forceinline__ float hw_exp2(float x) { return __builtin_amdgcn_exp2f(x); }

__device__ __forceinline__ uint32_t mbcnt64(uint64_t m) {
  return __builtin_amdgcn_mbcnt_hi((uint32_t)(m >> 32),
         __builtin_amdgcn_mbcnt_lo((uint32_t)m, 0u));
}

// 1-instruction rotate on device (v_alignbit_b32), plain on host
__host__ __device__ __forceinline__ uint32_t rotl32(uint32_t x, int r) {
#ifdef __HIP_DEVICE_COMPILE__
  return __builtin_amdgcn_alignbit(x, x, (uint32_t)(32 - r));
#else
  return (x << r) | (x >> (32 - r));
#endif
}

// ---- Threefry-2x32, 20 rounds, exactly JAX's schedule ----
__host__ __device__ __forceinline__ void tf2x32(uint32_t k0, uint32_t k1,
                                                uint32_t& x0, uint32_t& x1) {
  const uint32_t ks2 = k0 ^ k1 ^ 0x1BD11BDAu;
  x0 += k0; x1 += k1;
#define TF_RND(r) { x0 += x1; x1 = rotl32(x1, r); x1 ^= x0; }
  TF_RND(13) TF_RND(15) TF_RND(26) TF_RND(6)
  x0 += k1;  x1 += ks2 + 1u;
  TF_RND(17) TF_RND(29) TF_RND(16) TF_RND(24)
  x0 += ks2; x1 += k0 + 2u;
  TF_RND(13) TF_RND(15) TF_RND(26) TF_RND(6)
  x0 += k0;  x1 += k1 + 3u;
  TF_RND(17) TF_RND(29) TF_RND(16) TF_RND(24)
  x0 += k1;  x1 += ks2 + 4u;
  TF_RND(13) TF_RND(15) TF_RND(26) TF_RND(6)
  x0 += ks2; x1 += k0 + 5u;
#undef TF_RND
}

__device__ __forceinline__ float sim_fast(float x0, float x1, float xsq,
                                          float tx, float ty) {
  float tsq = tx * tx + ty * ty;
  float d2 = fmaxf(xsq + tsq - 2.0f * (x0 * tx + x1 * ty), 1e-12f);
  return 1.0f / (1.0f + A_C * hw_exp2(BB_C * hw_log2(d2)));
}

// t = (-ln u) * wf^-0.75 = exp(-score): rank DESC by score == rank ASC by t.
// u==0 (prob 2^-23) -> t=+inf -> lowest priority (JAX's clamp likewise never
// selects it). Flip bits so "select K largest keys" machinery is unchanged.
__device__ __forceinline__ uint32_t make_key(uint32_t bits, float w75n) {
  float f = __uint_as_float((bits >> 9) | 0x3f800000u) - 1.0f;   // u in [0,1)
  float t = hw_log2(f) * w75n;                                   // >0 (w75n<0)
  return ~__float_as_uint(t);
}

__global__ void prew_kernel(const float* __restrict__ wf,
                            float* __restrict__ w75n) {
  int i = blockIdx.x * 256 + threadIdx.x;
  if (i < NT_COLS) w75n[i] = -powf(wf[i], -0.75f);
}

// post-histogram scan + boundary find for one 11-bit digit at SHIFT.
// hist is PACKED: row A counts in low 16 bits, row B in high 16 bits.
template <int SHIFT>
__device__ __forceinline__ void scan_pass(
    uint32_t* hist, bool rezero,
    uint32_t& prefA, uint32_t& remA, uint32_t& prefB, uint32_t& remB,
    uint32_t* wsum, volatile uint32_t* sh_scal, int tid, int lane, int wv) {
  __syncthreads();
  uint2 av = ((uint2*)hist)[tid];               // bins 2tid, 2tid+1 (packed)
  if (rezero) ((uint2*)hist)[tid] = make_uint2(0u, 0u);
  uint32_t P = av.x + av.y;                     // packed pair total
  uint32_t ia = P;
#pragma unroll
  for (int off = 1; off < 64; off <<= 1) {      // packed in-wave suffix scan
    uint32_t u = __shfl_down(ia, off);
    if (lane + off < 64) ia += u;
  }
  if (lane == 0) wsum[wv] = ia;
  __syncthreads();
  uint32_t t = wsum[lane & 15], o = t;
#pragma unroll
  for (int off = 1; off < 16; off <<= 1) {      // packed wave-total suffix
    uint32_t u = __shfl_down(t, off);
    if (lane + off < 16) t += u;
  }
  uint32_t e = (uint32_t)__builtin_amdgcn_readlane((int)(t - o), wv);
  uint32_t S = e + (ia - P);                    // packed strictly-after sum
  uint32_t SA = S & 0xFFFFu, SB = S >> 16;
  uint32_t a0A = av.x & 0xFFFFu, a0B = av.x >> 16;
  uint32_t a1A = av.y & 0xFFFFu, a1B = av.y >> 16;
  {
    uint32_t gt1 = SA, ge1 = a1A + SA, gt0 = ge1, ge0 = a0A + ge1;
    if (ge0 >= remA && gt0 < remA) { sh_scal[0] = prefA | ((uint32_t)(2 * tid) << SHIFT); sh_scal[1] = remA - gt0; }
    if (ge1 >= remA && gt1 < remA) { sh_scal[0] = prefA | ((uint32_t)(2 * tid + 1) << SHIFT); sh_scal[1] = remA - gt1; }
  }
  {
    uint32_t gt1 = SB, ge1 = a1B + SB, gt0 = ge1, ge0 = a0B + ge1;
    if (ge0 >= remB && gt0 < remB) { sh_scal[2] = prefB | ((uint32_t)(2 * tid) << SHIFT); sh_scal[3] = remB - gt0; }
    if (ge1 >= remB && gt1 < remB) { sh_scal[2] = prefB | ((uint32_t)(2 * tid + 1) << SHIFT); sh_scal[3] = remB - gt1; }
  }
  __syncthreads();
  prefA = sh_scal[0]; remA = sh_scal[1];
  prefB = sh_scal[2]; remB = sh_scal[3];
}

__global__ __launch_bounds__(THREADS, 8) void cdr_pair_kernel(
    const float* __restrict__ x_emb, const float* __restrict__ t_emb,
    const float* __restrict__ w75n, const float* __restrict__ wf,
    const int* __restrict__ pos_idx,
    float* __restrict__ row_loss, float* __restrict__ out_atomic,
    uint32_t fk0, uint32_t fk1) {
  __shared__ uint32_t hist[NBINS];      // 8 KB, packed A|B
  __shared__ uint32_t sel[2048];        // 8 KB (2032 used)
  __shared__ uint32_t candK[2][CMAX];   // 1 KB
  __shared__ uint16_t candC[2][CMAX];   // 0.5 KB
  __shared__ uint32_t wsum[16];
  __shared__ uint32_t sh_scal[4];
  __shared__ uint32_t sh_cnt[2], sh_tie[2], sh_nsel;
  __shared__ uint32_t sh_theta[2], sh_need[2];
  __shared__ int sh_pos[2 * P_POS];
  __shared__ float shA[16], shB[16], sh_pp[16];

  const int r0 = blockIdx.x;            // 0..2047
  const int r1 = r0 + HALF_B;
  const int tid = threadIdx.x;
  const int lane = tid & 63;
  const int wv = tid >> 6;

  ((uint2*)hist)[tid] = make_uint2(0u, 0u);
  if (tid < P_POS) sh_pos[tid] = pos_idx[r0 * P_POS + tid];
  else if (tid < 2 * P_POS) sh_pos[tid] = pos_idx[r1 * P_POS + (tid - P_POS)];
  if (tid == 0) sh_nsel = 0u;
  if (tid < 2) { sh_cnt[tid] = 0u; sh_tie[tid] = 0u; }
  __syncthreads();

  // consecutive-cols layout: this thread owns cols [tid*8, tid*8+8)
  const int colbase = tid * EPT;
  uint32_t m0 = 0u, m1 = 0u;
#pragma unroll
  for (int p = 0; p < P_POS; ++p) {
    int c0 = sh_pos[p], c1 = sh_pos[P_POS + p];
    if ((c0 >> 3) == tid) m0 |= 1u << (c0 & 7);
    if ((c1 >> 3) == tid) m1 |= 1u << (c1 & 7);
  }

  float wv8[EPT];
  if (w75n) {
    const float4* w4 = (const float4*)w75n;
    float4 wA = w4[2 * tid], wB = w4[2 * tid + 1];
    wv8[0] = wA.x; wv8[1] = wA.y; wv8[2] = wA.z; wv8[3] = wA.w;
    wv8[4] = wB.x; wv8[5] = wB.y; wv8[6] = wB.z; wv8[7] = wB.w;
  } else {
#pragma unroll
    for (int i = 0; i < EPT; ++i)
      wv8[i] = -hw_exp2(-0.75f * hw_log2(wf[colbase + i]));
  }

  // ---- phase 1: threefry -> keys (regs) with FUSED pass-1 histogram ----
  uint32_t k0[EPT], k1[EPT];
  const uint32_t H = 16777216u;   // (B*NT)/2
  const uint32_t nbase = (uint32_t)(r0 * NT_COLS + colbase);
#pragma unroll
  for (int i = 0; i < EPT; ++i) {
    uint32_t xa = nbase + (uint32_t)i, xb = xa + H;
    tf2x32(fk0, fk1, xa, xb);
    uint32_t ka = make_key(xa, wv8[i]);
    uint32_t kb = make_key(xb, wv8[i]);
    ka = ((m0 >> i) & 1u) ? 0u : ka;
    kb = ((m1 >> i) & 1u) ? 0u : kb;
    k0[i] = ka; k1[i] = kb;
    atomicAdd(&hist[ka >> 21], 1u);          // row A: low 16 bits
    atomicAdd(&hist[kb >> 21], 0x10000u);    // row B: high 16 bits
  }

  // ---- phase 2: digit 1 scan, then guarded digit 2 ----
  uint32_t prefA = 0u, prefB = 0u, remA = K_NEG, remB = K_NEG;
  scan_pass<21>(hist, true, prefA, remA, prefB, remB,
                wsum, sh_scal, tid, lane, wv);
  const uint32_t PM11 = 0xFFE00000u;
#pragma unroll
  for (int i = 0; i < EPT; ++i) {
    uint32_t ka = k0[i];
    if ((ka & PM11) == prefA) atomicAdd(&hist[(ka >> 10) & 0x7FFu], 1u);
    uint32_t kb = k1[i];
    if ((kb & PM11) == prefB) atomicAdd(&hist[(kb >> 10) & 0x7FFu], 0x10000u);
  }
  scan_pass<10>(hist, false, prefA, remA, prefB, remB,
                wsum, sh_scal, tid, lane, wv);
  const uint32_t PM22 = 0xFFFFFC00u;

  // ---- phase 3a: compact selected cols; ONE sh_nsel atomic per wave per row.
  //      Build the 8 ballot masks in VGPRs first, then write with scalar
  //      running offsets (removes the 256-deep serialized atomic chain). ----
#pragma unroll
  for (int rsb = 0; rsb < 2; ++rsb) {
    uint64_t mask[EPT];
    uint32_t wavecnt = 0u;
    uint32_t pref = rsb ? prefB : prefA;
#pragma unroll
    for (int i = 0; i < EPT; ++i) {
      uint32_t k = rsb ? k1[i] : k0[i];
      uint32_t p22 = k & PM22;
      uint64_t mb = __ballot(p22 > pref);
      mask[i] = mb;
      wavecnt += (uint32_t)__popcll(mb);
      if (p22 == pref) {
        uint32_t s = atomicAdd(&sh_cnt[rsb], 1u);
        if (s < CMAX) { candK[rsb][s] = k; candC[rsb][s] = (uint16_t)(colbase + i); }
      }
    }
    uint32_t base = 0u;
    if (lane == 0) base = atomicAdd(&sh_nsel, wavecnt);
    base = (uint32_t)__builtin_amdgcn_readfirstlane((int)base);
#pragma unroll
    for (int i = 0; i < EPT; ++i) {
      uint64_t mb = mask[i];
      if ((mb >> lane) & 1ull)
        sel[base + mbcnt64(mb)] = (uint32_t)(colbase + i) | ((uint32_t)rsb << 13);
      base += (uint32_t)__popcll(mb);
    }
  }
  __syncthreads();

  // ---- phase 3b: resolve exact theta among the prefix-tied candidates ----
  if (tid < 2) {
    uint32_t c = sh_cnt[tid]; if (c > CMAX) c = CMAX;
    uint32_t rr = tid ? remB : remA;
    uint32_t th = 0u, nd = 0u;
    for (uint32_t j = 0; j < c; ++j) {
      uint32_t kj = candK[tid][j];
      uint32_t gt = 0u, eq = 0u;
      for (uint32_t l = 0; l < c; ++l) { gt += (candK[tid][l] > kj); eq += (candK[tid][l] == kj); }
      if (gt < rr && gt + eq >= rr) { th = kj; nd = rr - gt; }
    }
    sh_theta[tid] = th; sh_need[tid] = nd;
  }
  __syncthreads();

  // ---- phase 3c: append boundary candidates ----
  if (tid < 2 * CMAX) {
    const int rsb = tid >> 7;
    const uint32_t j = tid & (CMAX - 1);
    uint32_t c = sh_cnt[rsb]; if (c > CMAX) c = CMAX;
    if (j < c) {
      uint32_t k = candK[rsb][j];
      uint32_t th = sh_theta[rsb];
      bool inc = (k > th);
      if (k == th) inc = (atomicAdd(&sh_tie[rsb], 1u) < sh_need[rsb]);
      if (inc) {
        uint32_t s = atomicAdd(&sh_nsel, 1u);
        sel[s] = (uint32_t)candC[rsb][j] | ((uint32_t)rsb << 13);
      }
    }
  }
  __syncthreads();
  const uint32_t total = sh_nsel;   // == 2 * K_NEG

  const float xa0 = x_emb[r0 * 2], xa1 = x_emb[r0 * 2 + 1];
  const float xb0 = x_emb[r1 * 2], xb1 = x_emb[r1 * 2 + 1];
  const float qa = xa0 * xa0 + xa1 * xa1;
  const float qb = xb0 * xb0 + xb1 * xb1;
  const float2* temb2 = (const float2*)t_emb;

  // ---- phase 4: dense sweep over the 2032 selected entries ----
  float accA = 0.0f, accB = 0.0f;
  for (uint32_t j = tid; j < total; j += THREADS) {
    uint32_t e = sel[j];
    int col = e & 0x1FFFu;
    bool isB = (e & 0x2000u) != 0u;
    float2 t = temb2[col];
    float px = isB ? xb0 : xa0;
    float py = isB ? xb1 : xa1;
    float pq = isB ? qb : qa;
    float s = sim_fast(px, py, pq, t.x, t.y);
    float ez = hw_exp2(s * (INV_T * INV_LN2_F));
    if (isB) accB += ez; else accA += ez;
  }
#pragma unroll
  for (int off = 32; off > 0; off >>= 1) {
    accA += __shfl_down(accA, off);
    accB += __shfl_down(accB, off);
  }
  if (lane == 0) { shA[wv] = accA; shB[wv] = accB; }
  if (tid < 16) {
    int rowb = tid >> 3;
    int c = sh_pos[tid];
    float2 t = temb2[c];
    float px = rowb ? xb0 : xa0;
    float py = rowb ? xb1 : xa1;
    float pq = rowb ? qb : qa;
    sh_pp[tid] = sim_fast(px, py, pq, t.x, t.y);
  }
  __syncthreads();

  if (tid < 2) {
    float s = 0.0f;
#pragma unroll
    for (int w = 0; w < 16; ++w) s += tid ? shB[w] : shA[w];
    float ps = 0.0f;
#pragma unroll
    for (int p = 0; p < P_POS; ++p) ps += sh_pp[tid * P_POS + p];
    float pos = ps * (1.0f / P_POS);
    float zpos = pos * INV_T;
    float S = s + hw_exp2(zpos * INV_LN2_F) + N_PAD;
    float loss = logf(S) - zpos;
    int r = tid ? r1 : r0;
    if (row_loss) row_loss[r] = loss;
    else atomicAdd(out_atomic, loss * (1.0f / B_ROWS));
  }
}

__global__ __launch_bounds__(256) void cdr_reduce_kernel(
    const float* __restrict__ row_loss, float* __restrict__ out) {
  __shared__ float part[4];
  float s = 0.0f;
  for (int i = threadIdx.x; i < B_ROWS; i += 256) s += row_loss[i];
#pragma unroll
  for (int off = 32; off > 0; off >>= 1) s += __shfl_down(s, off);
  if ((threadIdx.x & 63) == 0) part[threadIdx.x >> 6] = s;
  __syncthreads();
  if (threadIdx.x == 0)
    out[0] = (part[0] + part[1] + part[2] + part[3]) * (1.0f / B_ROWS);
}

__global__ void cdr_zero_kernel(float* __restrict__ out) { out[0] = 0.0f; }

extern "C" void kernel_launch(void* const* d_in, const int* in_sizes, int n_in,
                              void* d_out, int out_size, void* d_ws, size_t ws_size,
                              hipStream_t stream) {
  const float* x_emb = (const float*)d_in[0];
  const float* t_emb = (const float*)d_in[1];
  const float* wf    = (const float*)d_in[2];
  const int*   pidx  = (const int*)d_in[3];
  float* out = (float*)d_out;

  uint32_t fk0 = 0u, fk1 = 1u;
  tf2x32(0u, 0u, fk0, fk1);

  const bool has_w75 = (ws_size >= (size_t)(NT_COLS + B_ROWS) * sizeof(float));
  const bool has_rl  = (ws_size >= (size_t)B_ROWS * sizeof(float));

  float* w75n = nullptr;
  float* row_loss = nullptr;
  if (has_w75) { w75n = (float*)d_ws; row_loss = (float*)d_ws + NT_COLS; }
  else if (has_rl) { row_loss = (float*)d_ws; }

  if (has_w75) {
    hipLaunchKernelGGL(prew_kernel, dim3(NT_COLS / 256), dim3(256), 0, stream,
                       wf, w75n);
  }
  if (!row_loss) {
    hipLaunchKernelGGL(cdr_zero_kernel, dim3(1), dim3(1), 0, stream, out);
  }
  hipLaunchKernelGGL(cdr_pair_kernel, dim3(HALF_B), dim3(THREADS), 0, stream,
                     x_emb, t_emb, w75n, wf, pidx, row_loss, out, fk0, fk1);
  if (row_loss) {
    hipLaunchKernelGGL(cdr_reduce_kernel, dim3(1), dim3(256), 0, stream,
                       row_loss, out);
  }
}

// Round 12
// 80.095 us; speedup vs baseline: 1.1419x; 1.0211x over previous
//
#include <hip/hip_runtime.h>
#include <cstdint>
#include <math.h>

#define B_ROWS 4096
#define HALF_B 2048
#define NT_COLS 8192
#define P_POS 8
#define K_NEG 1016
#define N_PAD 3079.0f          // B - (1+K)
#define A_C 1.57694f
#define BB_C 0.89506f
#define INV_T 6.66666666667f
#define THREADS 1024
#define EPT 8                  // NT_COLS / THREADS
#define LN2_F 0.69314718056f
#define INV_LN2_F 1.44269504089f
#define NBINS 1024
#define CMAX 128

__device__ __forceinline__ float hw_log2(float x) { return __builtin_amdgcn_logf(x); }
__device__ __forceinline__ float hw_exp2(float x) { return __builtin_amdgcn_exp2f(x); }

__device__ __forceinline__ uint32_t mbcnt64(uint64_t m) {
  return __builtin_amdgcn_mbcnt_hi((uint32_t)(m >> 32),
         __builtin_amdgcn_mbcnt_lo((uint32_t)m, 0u));
}

// 1-instruction rotate on device (v_alignbit_b32), plain on host
__host__ __device__ __forceinline__ uint32_t rotl32(uint32_t x, int r) {
#ifdef __HIP_DEVICE_COMPILE__
  return __builtin_amdgcn_alignbit(x, x, (uint32_t)(32 - r));
#else
  return (x << r) | (x >> (32 - r));
#endif
}

// ---- Threefry-2x32, 20 rounds, exactly JAX's schedule ----
__host__ __device__ __forceinline__ void tf2x32(uint32_t k0, uint32_t k1,
                                                uint32_t& x0, uint32_t& x1) {
  const uint32_t ks2 = k0 ^ k1 ^ 0x1BD11BDAu;
  x0 += k0; x1 += k1;
#define TF_RND(r) { x0 += x1; x1 = rotl32(x1, r); x1 ^= x0; }
  TF_RND(13) TF_RND(15) TF_RND(26) TF_RND(6)
  x0 += k1;  x1 += ks2 + 1u;
  TF_RND(17) TF_RND(29) TF_RND(16) TF_RND(24)
  x0 += ks2; x1 += k0 + 2u;
  TF_RND(13) TF_RND(15) TF_RND(26) TF_RND(6)
  x0 += k0;  x1 += k1 + 3u;
  TF_RND(17) TF_RND(29) TF_RND(16) TF_RND(24)
  x0 += k1;  x1 += ks2 + 4u;
  TF_RND(13) TF_RND(15) TF_RND(26) TF_RND(6)
  x0 += ks2; x1 += k0 + 5u;
#undef TF_RND
}

__device__ __forceinline__ float sim_fast(float x0, float x1, float xsq,
                                          float tx, float ty) {
  float tsq = tx * tx + ty * ty;
  float d2 = fmaxf(xsq + tsq - 2.0f * (x0 * tx + x1 * ty), 1e-12f);
  return 1.0f / (1.0f + A_C * hw_exp2(BB_C * hw_log2(d2)));
}

// t = (-ln u) * wf^-0.75 = exp(-score): rank DESC by score == rank ASC by t.
// Real keys = ~t_bits with t>0 -> bit31 is ALWAYS 1; masked keys are 0.
// So radix digits need only 10 bits below the constant top bit.
__device__ __forceinline__ uint32_t make_key(uint32_t bits, float w75n) {
  float f = __uint_as_float((bits >> 9) | 0x3f800000u) - 1.0f;   // u in [0,1)
  float t = hw_log2(f) * w75n;                                   // >0 (w75n<0)
  return ~__float_as_uint(t);
}

__global__ void prew_kernel(const float* __restrict__ wf,
                            float* __restrict__ w75n) {
  int i = blockIdx.x * 256 + threadIdx.x;
  if (i < NT_COLS) w75n[i] = -powf(wf[i], -0.75f);
}

// post-histogram scan + boundary find over 1024 bins (packed A|B 16-bit).
// Running class P: init 1 (constant key top bit); update P = (P<<10)|bin.
__device__ __forceinline__ void scan_pass(
    uint32_t* hist, bool rezero,
    uint32_t& PA, uint32_t& remA, uint32_t& PB, uint32_t& remB,
    uint32_t* wsum, volatile uint32_t* sh_scal, int tid, int lane, int wv) {
  __syncthreads();
  if (tid < 512) {
    uint2 av = ((uint2*)hist)[tid];             // bins 2tid, 2tid+1 (packed)
    if (rezero) ((uint2*)hist)[tid] = make_uint2(0u, 0u);
    uint32_t P2 = av.x + av.y;                  // packed pair total
    uint32_t ia = P2;
#pragma unroll
    for (int off = 1; off < 64; off <<= 1) {    // packed in-wave suffix scan
      uint32_t u = __shfl_down(ia, off);
      if (lane + off < 64) ia += u;
    }
    if (lane == 0) wsum[wv] = ia;               // wv in 0..7
    __syncthreads();
    uint32_t t = wsum[lane & 7], o = t;
#pragma unroll
    for (int off = 1; off < 8; off <<= 1) {     // packed wave-total suffix
      uint32_t u = __shfl_down(t, off);
      if ((lane & 7) + off < 8) t += u;
    }
    uint32_t e = (uint32_t)__builtin_amdgcn_readlane((int)(t - o), wv);
    uint32_t S = e + (ia - P2);                 // packed strictly-after sum
    uint32_t SA = S & 0xFFFFu, SB = S >> 16;
    uint32_t a0A = av.x & 0xFFFFu, a0B = av.x >> 16;
    uint32_t a1A = av.y & 0xFFFFu, a1B = av.y >> 16;
    {
      uint32_t gt1 = SA, ge1 = a1A + SA, gt0 = ge1, ge0 = a0A + ge1;
      if (ge0 >= remA && gt0 < remA) { sh_scal[0] = (PA << 10) | (uint32_t)(2 * tid); sh_scal[1] = remA - gt0; }
      if (ge1 >= remA && gt1 < remA) { sh_scal[0] = (PA << 10) | (uint32_t)(2 * tid + 1); sh_scal[1] = remA - gt1; }
    }
    {
      uint32_t gt1 = SB, ge1 = a1B + SB, gt0 = ge1, ge0 = a0B + ge1;
      if (ge0 >= remB && gt0 < remB) { sh_scal[2] = (PB << 10) | (uint32_t)(2 * tid); sh_scal[3] = remB - gt0; }
      if (ge1 >= remB && gt1 < remB) { sh_scal[2] = (PB << 10) | (uint32_t)(2 * tid + 1); sh_scal[3] = remB - gt1; }
    }
  } else {
    __syncthreads();
  }
  __syncthreads();
  PA = sh_scal[0]; remA = sh_scal[1];
  PB = sh_scal[2]; remB = sh_scal[3];
}

__global__ __launch_bounds__(THREADS, 8) void cdr_pair_kernel(
    const float* __restrict__ x_emb, const float* __restrict__ t_emb,
    const float* __restrict__ w75n, const float* __restrict__ wf,
    const int* __restrict__ pos_idx,
    float* __restrict__ row_loss, float* __restrict__ out_atomic,
    uint32_t fk0, uint32_t fk1) {
  __shared__ uint32_t hist[NBINS];      // 4 KB, packed A|B
  __shared__ uint32_t sel[2048];        // 8 KB (2032 used)
  __shared__ uint32_t candK[2][CMAX];   // 1 KB
  __shared__ uint16_t candC[2][CMAX];   // 0.5 KB
  __shared__ uint32_t wsum[8];
  __shared__ uint32_t sh_scal[4];
  __shared__ uint32_t sh_cnt[2], sh_nsel;
  __shared__ int sh_pos[2 * P_POS];
  __shared__ float shA[16], shB[16], sh_pp[16];

  const int r0 = blockIdx.x;            // 0..2047
  const int r1 = r0 + HALF_B;
  const int tid = threadIdx.x;
  const int lane = tid & 63;
  const int wv = tid >> 6;

  if (tid < 512) ((uint2*)hist)[tid] = make_uint2(0u, 0u);
  if (tid < P_POS) sh_pos[tid] = pos_idx[r0 * P_POS + tid];
  else if (tid < 2 * P_POS) sh_pos[tid] = pos_idx[r1 * P_POS + (tid - P_POS)];
  if (tid == 0) sh_nsel = 0u;
  if (tid < 2) sh_cnt[tid] = 0u;
  __syncthreads();

  // consecutive-cols layout: this thread owns cols [tid*8, tid*8+8)
  const int colbase = tid * EPT;
  uint32_t m0 = 0u, m1 = 0u;
#pragma unroll
  for (int p = 0; p < P_POS; ++p) {
    int c0 = sh_pos[p], c1 = sh_pos[P_POS + p];
    if ((c0 >> 3) == tid) m0 |= 1u << (c0 & 7);
    if ((c1 >> 3) == tid) m1 |= 1u << (c1 & 7);
  }

  float wv8[EPT];
  if (w75n) {
    const float4* w4 = (const float4*)w75n;
    float4 wA = w4[2 * tid], wB = w4[2 * tid + 1];
    wv8[0] = wA.x; wv8[1] = wA.y; wv8[2] = wA.z; wv8[3] = wA.w;
    wv8[4] = wB.x; wv8[5] = wB.y; wv8[6] = wB.z; wv8[7] = wB.w;
  } else {
#pragma unroll
    for (int i = 0; i < EPT; ++i)
      wv8[i] = -hw_exp2(-0.75f * hw_log2(wf[colbase + i]));
  }

  // ---- phase 1: threefry -> keys (regs) with FUSED pass-1 histogram ----
  uint32_t k0[EPT], k1[EPT];
  const uint32_t H = 16777216u;   // (B*NT)/2
  const uint32_t nbase = (uint32_t)(r0 * NT_COLS + colbase);
#pragma unroll
  for (int i = 0; i < EPT; ++i) {
    uint32_t xa = nbase + (uint32_t)i, xb = xa + H;
    tf2x32(fk0, fk1, xa, xb);
    uint32_t ka = make_key(xa, wv8[i]);
    uint32_t kb = make_key(xb, wv8[i]);
    ka = ((m0 >> i) & 1u) ? 0u : ka;
    kb = ((m1 >> i) & 1u) ? 0u : kb;
    k0[i] = ka; k1[i] = kb;
    atomicAdd(&hist[(ka >> 21) & 0x3FFu], 1u);        // row A: low 16 bits
    atomicAdd(&hist[(kb >> 21) & 0x3FFu], 0x10000u);  // row B: high 16 bits
  }

  // ---- phase 2: digit 1 scan, then guarded digit 2 ----
  uint32_t PA = 1u, PB = 1u, remA = K_NEG, remB = K_NEG;
  scan_pass(hist, true, PA, remA, PB, remB, wsum, sh_scal, tid, lane, wv);
#pragma unroll
  for (int i = 0; i < EPT; ++i) {
    uint32_t ka = k0[i];
    if ((ka >> 21) == PA) atomicAdd(&hist[(ka >> 11) & 0x3FFu], 1u);
    uint32_t kb = k1[i];
    if ((kb >> 21) == PB) atomicAdd(&hist[(kb >> 11) & 0x3FFu], 0x10000u);
  }
  scan_pass(hist, false, PA, remA, PB, remB, wsum, sh_scal, tid, lane, wv);
  // PA, PB are now 21-bit classes == (key >> 11) of the boundary key

  // ---- phase 3a: compact selected cols; ONE sh_nsel atomic per wave per row.
  //      Build the 8 ballot masks in VGPRs first, then write with scalar
  //      running offsets. ----
#pragma unroll
  for (int rsb = 0; rsb < 2; ++rsb) {
    uint64_t mask[EPT];
    uint32_t wavecnt = 0u;
    uint32_t pref = rsb ? PB : PA;
#pragma unroll
    for (int i = 0; i < EPT; ++i) {
      uint32_t kc = (rsb ? k1[i] : k0[i]) >> 11;
      uint64_t mb = __ballot(kc > pref);
      mask[i] = mb;
      wavecnt += (uint32_t)__popcll(mb);
      if (kc == pref) {
        uint32_t s = atomicAdd(&sh_cnt[rsb], 1u);
        if (s < CMAX) { candK[rsb][s] = rsb ? k1[i] : k0[i]; candC[rsb][s] = (uint16_t)(colbase + i); }
      }
    }
    uint32_t base = 0u;
    if (lane == 0) base = atomicAdd(&sh_nsel, wavecnt);
    base = (uint32_t)__builtin_amdgcn_readfirstlane((int)base);
#pragma unroll
    for (int i = 0; i < EPT; ++i) {
      uint64_t mb = mask[i];
      if ((mb >> lane) & 1ull)
        sel[base + mbcnt64(mb)] = (uint32_t)(colbase + i) | ((uint32_t)rsb << 13);
      base += (uint32_t)__popcll(mb);
    }
  }
  __syncthreads();

  // ---- phase 3b: parallel rank-based boundary resolve (cand-array order) ----
  if (tid < 2 * CMAX) {
    const int rsb = tid >> 7;
    const uint32_t j = tid & (CMAX - 1);
    uint32_t c = sh_cnt[rsb]; if (c > CMAX) c = CMAX;
    uint32_t rr = rsb ? remB : remA;
    if (j < c) {
      uint32_t kj = candK[rsb][j];
      uint32_t rank = 0u;
      for (uint32_t l = 0; l < c; ++l) {
        uint32_t kl = candK[rsb][l];
        rank += (kl > kj) || ((kl == kj) && (l < j));
      }
      if (rank < rr) {
        uint32_t s = atomicAdd(&sh_nsel, 1u);
        sel[s] = (uint32_t)candC[rsb][j] | ((uint32_t)rsb << 13);
      }
    }
  }
  __syncthreads();
  const uint32_t total = sh_nsel;   // == 2 * K_NEG

  const float xa0 = x_emb[r0 * 2], xa1 = x_emb[r0 * 2 + 1];
  const float xb0 = x_emb[r1 * 2], xb1 = x_emb[r1 * 2 + 1];
  const float qa = xa0 * xa0 + xa1 * xa1;
  const float qb = xb0 * xb0 + xb1 * xb1;
  const float2* temb2 = (const float2*)t_emb;

  // ---- phase 4: dense sweep over the 2032 selected entries ----
  float accA = 0.0f, accB = 0.0f;
  for (uint32_t j = tid; j < total; j += THREADS) {
    uint32_t e = sel[j];
    int col = e & 0x1FFFu;
    bool isB = (e & 0x2000u) != 0u;
    float2 t = temb2[col];
    float px = isB ? xb0 : xa0;
    float py = isB ? xb1 : xa1;
    float pq = isB ? qb : qa;
    float s = sim_fast(px, py, pq, t.x, t.y);
    float ez = hw_exp2(s * (INV_T * INV_LN2_F));
    if (isB) accB += ez; else accA += ez;
  }
#pragma unroll
  for (int off = 32; off > 0; off >>= 1) {
    accA += __shfl_down(accA, off);
    accB += __shfl_down(accB, off);
  }
  if (lane == 0) { shA[wv] = accA; shB[wv] = accB; }
  if (tid < 16) {
    int rowb = tid >> 3;
    int c = sh_pos[tid];
    float2 t = temb2[c];
    float px = rowb ? xb0 : xa0;
    float py = rowb ? xb1 : xa1;
    float pq = rowb ? qb : qa;
    sh_pp[tid] = sim_fast(px, py, pq, t.x, t.y);
  }
  __syncthreads();

  if (tid < 2) {
    float s = 0.0f;
#pragma unroll
    for (int w = 0; w < 16; ++w) s += tid ? shB[w] : shA[w];
    float ps = 0.0f;
#pragma unroll
    for (int p = 0; p < P_POS; ++p) ps += sh_pp[tid * P_POS + p];
    float pos = ps * (1.0f / P_POS);
    float zpos = pos * INV_T;
    float S = s + hw_exp2(zpos * INV_LN2_F) + N_PAD;
    float loss = logf(S) - zpos;
    int r = tid ? r1 : r0;
    if (row_loss) row_loss[r] = loss;
    else atomicAdd(out_atomic, loss * (1.0f / B_ROWS));
  }
}

__global__ __launch_bounds__(256) void cdr_reduce_kernel(
    const float* __restrict__ row_loss, float* __restrict__ out) {
  __shared__ float part[4];
  float s = 0.0f;
  for (int i = threadIdx.x; i < B_ROWS; i += 256) s += row_loss[i];
#pragma unroll
  for (int off = 32; off > 0; off >>= 1) s += __shfl_down(s, off);
  if ((threadIdx.x & 63) == 0) part[threadIdx.x >> 6] = s;
  __syncthreads();
  if (threadIdx.x == 0)
    out[0] = (part[0] + part[1] + part[2] + part[3]) * (1.0f / B_ROWS);
}

__global__ void cdr_zero_kernel(float* __restrict__ out) { out[0] = 0.0f; }

extern "C" void kernel_launch(void* const* d_in, const int* in_sizes, int n_in,
                              void* d_out, int out_size, void* d_ws, size_t ws_size,
                              hipStream_t stream) {
  const float* x_emb = (const float*)d_in[0];
  const float* t_emb = (const float*)d_in[1];
  const float* wf    = (const float*)d_in[2];
  const int*   pidx  = (const int*)d_in[3];
  float* out = (float*)d_out;

  uint32_t fk0 = 0u, fk1 = 1u;
  tf2x32(0u, 0u, fk0, fk1);

  const bool has_w75 = (ws_size >= (size_t)(NT_COLS + B_ROWS) * sizeof(float));
  const bool has_rl  = (ws_size >= (size_t)B_ROWS * sizeof(float));

  float* w75n = nullptr;
  float* row_loss = nullptr;
  if (has_w75) { w75n = (float*)d_ws; row_loss = (float*)d_ws + NT_COLS; }
  else if (has_rl) { row_loss = (float*)d_ws; }

  if (has_w75) {
    hipLaunchKernelGGL(prew_kernel, dim3(NT_COLS / 256), dim3(256), 0, stream,
                       wf, w75n);
  }
  if (!row_loss) {
    hipLaunchKernelGGL(cdr_zero_kernel, dim3(1), dim3(1), 0, stream, out);
  }
  hipLaunchKernelGGL(cdr_pair_kernel, dim3(HALF_B), dim3(THREADS), 0, stream,
                     x_emb, t_emb, w75n, wf, pidx, row_loss, out, fk0, fk1);
  if (row_loss) {
    hipLaunchKernelGGL(cdr_reduce_kernel, dim3(1), dim3(256), 0, stream,
                       row_loss, out);
  }
}

// Round 13
// 78.414 us; speedup vs baseline: 1.1664x; 1.0214x over previous
//
#include <hip/hip_runtime.h>
#include <cstdint>
#include <math.h>

#define B_ROWS 4096
#define HALF_B 2048
#define NT_COLS 8192
#define P_POS 8
#define K_NEG 1016
#define N_PAD 3079.0f          // B - (1+K)
#define A_C 1.57694f
#define BB_C 0.89506f
#define INV_T 6.66666666667f
#define THREADS 1024
#define EPT 8                  // NT_COLS / THREADS
#define LN2_F 0.69314718056f
#define INV_LN2_F 1.44269504089f
#define NBINS 2048
#define CMAX 128

__device__ __forceinline__ float hw_log2(float x) { return __builtin_amdgcn_logf(x); }
__device__ __forceinline__ float hw_exp2(float x) { return __builtin_amdgcn_exp2f(x); }

__device__ __forceinline__ uint32_t mbcnt64(uint64_t m) {
  return __builtin_amdgcn_mbcnt_hi((uint32_t)(m >> 32),
         __builtin_amdgcn_mbcnt_lo((uint32_t)m, 0u));
}

// 1-instruction rotate on device (v_alignbit_b32), plain on host
__host__ __device__ __forceinline__ uint32_t rotl32(uint32_t x, int r) {
#ifdef __HIP_DEVICE_COMPILE__
  return __builtin_amdgcn_alignbit(x, x, (uint32_t)(32 - r));
#else
  return (x << r) | (x >> (32 - r));
#endif
}

// ---- Threefry-2x32, 20 rounds, exactly JAX's schedule ----
__host__ __device__ __forceinline__ void tf2x32(uint32_t k0, uint32_t k1,
                                                uint32_t& x0, uint32_t& x1) {
  const uint32_t ks2 = k0 ^ k1 ^ 0x1BD11BDAu;
  x0 += k0; x1 += k1;
#define TF_RND(r) { x0 += x1; x1 = rotl32(x1, r); x1 ^= x0; }
  TF_RND(13) TF_RND(15) TF_RND(26) TF_RND(6)
  x0 += k1;  x1 += ks2 + 1u;
  TF_RND(17) TF_RND(29) TF_RND(16) TF_RND(24)
  x0 += ks2; x1 += k0 + 2u;
  TF_RND(13) TF_RND(15) TF_RND(26) TF_RND(6)
  x0 += k0;  x1 += k1 + 3u;
  TF_RND(17) TF_RND(29) TF_RND(16) TF_RND(24)
  x0 += k1;  x1 += ks2 + 4u;
  TF_RND(13) TF_RND(15) TF_RND(26) TF_RND(6)
  x0 += ks2; x1 += k0 + 5u;
#undef TF_RND
}

__device__ __forceinline__ float sim_fast(float x0, float x1, float xsq,
                                          float tx, float ty) {
  float tsq = tx * tx + ty * ty;
  float d2 = fmaxf(xsq + tsq - 2.0f * (x0 * tx + x1 * ty), 1e-12f);
  return 1.0f / (1.0f + A_C * hw_exp2(BB_C * hw_log2(d2)));
}

// t = (-ln u) * wf^-0.75 = exp(-score): rank DESC by score == rank ASC by t.
// Real keys = ~t_bits with t>0 -> bit31 ALWAYS 1 -> key>>21 in [1024,2048).
// Masked keys are 0 -> bin 0, outside the scanned range.
__device__ __forceinline__ uint32_t make_key(uint32_t bits, float w75n) {
  float f = __uint_as_float((bits >> 9) | 0x3f800000u) - 1.0f;   // u in [0,1)
  float t = hw_log2(f) * w75n;                                   // >0 (w75n<0)
  return ~__float_as_uint(t);
}

__global__ void prew_kernel(const float* __restrict__ wf,
                            float* __restrict__ w75n) {
  int i = blockIdx.x * 256 + threadIdx.x;
  if (i < NT_COLS) w75n[i] = -powf(wf[i], -0.75f);
}

// post-histogram scan + boundary find over 1024 bins starting at pair index
// `pairbase` (packed A|B 16-bit counts). Boundary class written as
// cbase + absolute bin index. If zero_bin0, tid0 clears hist[0] (masked-key
// counts) inside this barrier window so pass-2 bins [0,1024) start clean.
__device__ __forceinline__ void scan_pass(
    uint32_t* hist, int pairbase, bool zero_bin0,
    uint32_t cbaseA, uint32_t cbaseB,
    uint32_t& PA, uint32_t& remA, uint32_t& PB, uint32_t& remB,
    uint32_t* wsum, volatile uint32_t* sh_scal, int tid, int lane, int wv) {
  __syncthreads();
  if (tid < 512) {
    uint2 av = ((uint2*)hist)[pairbase + tid];  // bins 2(pb+tid), +1 (packed)
    if (zero_bin0 && tid == 0) hist[0] = 0u;
    uint32_t P2 = av.x + av.y;                  // packed pair total
    uint32_t ia = P2;
#pragma unroll
    for (int off = 1; off < 64; off <<= 1) {    // packed in-wave suffix scan
      uint32_t u = __shfl_down(ia, off);
      if (lane + off < 64) ia += u;
    }
    if (lane == 0) wsum[wv] = ia;               // wv in 0..7
    __syncthreads();
    uint32_t t = wsum[lane & 7], o = t;
#pragma unroll
    for (int off = 1; off < 8; off <<= 1) {     // packed wave-total suffix
      uint32_t u = __shfl_down(t, off);
      if ((lane & 7) + off < 8) t += u;
    }
    uint32_t e = (uint32_t)__builtin_amdgcn_readlane((int)(t - o), wv);
    uint32_t S = e + (ia - P2);                 // packed strictly-after sum
    uint32_t SA = S & 0xFFFFu, SB = S >> 16;
    uint32_t a0A = av.x & 0xFFFFu, a0B = av.x >> 16;
    uint32_t a1A = av.y & 0xFFFFu, a1B = av.y >> 16;
    uint32_t bin0 = 2u * (uint32_t)(pairbase + tid);
    {
      uint32_t gt1 = SA, ge1 = a1A + SA, gt0 = ge1, ge0 = a0A + ge1;
      if (ge0 >= remA && gt0 < remA) { sh_scal[0] = cbaseA + bin0; sh_scal[1] = remA - gt0; }
      if (ge1 >= remA && gt1 < remA) { sh_scal[0] = cbaseA + bin0 + 1u; sh_scal[1] = remA - gt1; }
    }
    {
      uint32_t gt1 = SB, ge1 = a1B + SB, gt0 = ge1, ge0 = a0B + ge1;
      if (ge0 >= remB && gt0 < remB) { sh_scal[2] = cbaseB + bin0; sh_scal[3] = remB - gt0; }
      if (ge1 >= remB && gt1 < remB) { sh_scal[2] = cbaseB + bin0 + 1u; sh_scal[3] = remB - gt1; }
    }
  } else {
    __syncthreads();
  }
  __syncthreads();
  PA = sh_scal[0]; remA = sh_scal[1];
  PB = sh_scal[2]; remB = sh_scal[3];
}

__global__ __launch_bounds__(THREADS, 8) void cdr_pair_kernel(
    const float* __restrict__ x_emb, const float* __restrict__ t_emb,
    const float* __restrict__ w75n, const float* __restrict__ wf,
    const int* __restrict__ pos_idx,
    float* __restrict__ row_loss, float* __restrict__ out_atomic,
    uint32_t fk0, uint32_t fk1) {
  __shared__ uint32_t hist[NBINS];      // 8 KB, packed A|B
  __shared__ uint32_t sel[2048];        // 8 KB (2032 used)
  __shared__ uint32_t candK[2][CMAX];   // 1 KB
  __shared__ uint16_t candC[2][CMAX];   // 0.5 KB
  __shared__ uint32_t wsum[8];
  __shared__ uint32_t sh_scal[4];
  __shared__ uint32_t sh_cnt[2], sh_nsel;
  __shared__ int sh_pos[2 * P_POS];
  __shared__ float shA[16], shB[16], sh_pp[16];

  const int r0 = blockIdx.x;            // 0..2047
  const int r1 = r0 + HALF_B;
  const int tid = threadIdx.x;
  const int lane = tid & 63;
  const int wv = tid >> 6;

  ((uint2*)hist)[tid] = make_uint2(0u, 0u);   // all 2048 words
  if (tid < P_POS) sh_pos[tid] = pos_idx[r0 * P_POS + tid];
  else if (tid < 2 * P_POS) sh_pos[tid] = pos_idx[r1 * P_POS + (tid - P_POS)];
  if (tid == 0) sh_nsel = 0u;
  if (tid < 2) sh_cnt[tid] = 0u;
  __syncthreads();

  // consecutive-cols layout: this thread owns cols [tid*8, tid*8+8)
  const int colbase = tid * EPT;
  uint32_t m0 = 0u, m1 = 0u;
#pragma unroll
  for (int p = 0; p < P_POS; ++p) {
    int c0 = sh_pos[p], c1 = sh_pos[P_POS + p];
    if ((c0 >> 3) == tid) m0 |= 1u << (c0 & 7);
    if ((c1 >> 3) == tid) m1 |= 1u << (c1 & 7);
  }

  float wv8[EPT];
  if (w75n) {
    const float4* w4 = (const float4*)w75n;
    float4 wA = w4[2 * tid], wB = w4[2 * tid + 1];
    wv8[0] = wA.x; wv8[1] = wA.y; wv8[2] = wA.z; wv8[3] = wA.w;
    wv8[4] = wB.x; wv8[5] = wB.y; wv8[6] = wB.z; wv8[7] = wB.w;
  } else {
#pragma unroll
    for (int i = 0; i < EPT; ++i)
      wv8[i] = -hw_exp2(-0.75f * hw_log2(wf[colbase + i]));
  }

  // ---- phase 1: threefry -> keys (regs) with FUSED pass-1 histogram ----
  uint32_t k0[EPT], k1[EPT];
  const uint32_t H = 16777216u;   // (B*NT)/2
  const uint32_t nbase = (uint32_t)(r0 * NT_COLS + colbase);
#pragma unroll
  for (int i = 0; i < EPT; ++i) {
    uint32_t xa = nbase + (uint32_t)i, xb = xa + H;
    tf2x32(fk0, fk1, xa, xb);
    uint32_t ka = make_key(xa, wv8[i]);
    uint32_t kb = make_key(xb, wv8[i]);
    ka = ((m0 >> i) & 1u) ? 0u : ka;
    kb = ((m1 >> i) & 1u) ? 0u : kb;
    k0[i] = ka; k1[i] = kb;
    atomicAdd(&hist[ka >> 21], 1u);          // row A: low 16 bits
    atomicAdd(&hist[kb >> 21], 0x10000u);    // row B: high 16 bits
  }

  // ---- phase 2: digit-1 scan over bins [1024,2048), guarded digit 2 over
  //      bins [0,1024) (clean: pass 1 never touched them except bin 0) ----
  uint32_t PA = 0u, PB = 0u, remA = K_NEG, remB = K_NEG;
  scan_pass(hist, 512, true, 0u, 0u, PA, remA, PB, remB,
            wsum, sh_scal, tid, lane, wv);
  // PA,PB = absolute class-10 = key>>21 of boundary, in [1024,2048)
#pragma unroll
  for (int i = 0; i < EPT; ++i) {
    uint32_t ka = k0[i];
    if ((ka >> 21) == PA) atomicAdd(&hist[(ka >> 11) & 0x3FFu], 1u);
    uint32_t kb = k1[i];
    if ((kb >> 21) == PB) atomicAdd(&hist[(kb >> 11) & 0x3FFu], 0x10000u);
  }
  scan_pass(hist, 0, false, PA << 10, PB << 10, PA, remA, PB, remB,
            wsum, sh_scal, tid, lane, wv);
  // PA, PB are now 21-bit classes == (key >> 11) of the boundary key

  // ---- phase 3a: compact selected cols; ONE sh_nsel atomic per wave per row.
  //      Ballot masks + per-thread predicate mask in VGPRs, then write with
  //      scalar running offsets. ----
#pragma unroll
  for (int rsb = 0; rsb < 2; ++rsb) {
    uint64_t mask[EPT];
    uint32_t pm = 0u, wavecnt = 0u;
    uint32_t pref = rsb ? PB : PA;
#pragma unroll
    for (int i = 0; i < EPT; ++i) {
      uint32_t kk = rsb ? k1[i] : k0[i];
      uint32_t kc = kk >> 11;
      bool d = kc > pref;
      uint64_t mb = __ballot(d);
      mask[i] = mb;
      pm |= d ? (1u << i) : 0u;
      wavecnt += (uint32_t)__popcll(mb);
      if (kc == pref) {
        uint32_t s = atomicAdd(&sh_cnt[rsb], 1u);
        if (s < CMAX) { candK[rsb][s] = kk; candC[rsb][s] = (uint16_t)(colbase + i); }
      }
    }
    uint32_t base = 0u;
    if (lane == 0) base = atomicAdd(&sh_nsel, wavecnt);
    base = (uint32_t)__builtin_amdgcn_readfirstlane((int)base);
#pragma unroll
    for (int i = 0; i < EPT; ++i) {
      if ((pm >> i) & 1u)
        sel[base + mbcnt64(mask[i])] = (uint32_t)(colbase + i) | ((uint32_t)rsb << 13);
      base += (uint32_t)__popcll(mask[i]);
    }
  }
  __syncthreads();

  // ---- phase 3b: parallel rank-based boundary resolve (cand-array order) ----
  if (tid < 2 * CMAX) {
    const int rsb = tid >> 7;
    const uint32_t j = tid & (CMAX - 1);
    uint32_t c = sh_cnt[rsb]; if (c > CMAX) c = CMAX;
    uint32_t rr = rsb ? remB : remA;
    if (j < c) {
      uint32_t kj = candK[rsb][j];
      uint32_t rank = 0u;
      for (uint32_t l = 0; l < c; ++l) {
        uint32_t kl = candK[rsb][l];
        rank += (kl > kj) || ((kl == kj) && (l < j));
      }
      if (rank < rr) {
        uint32_t s = atomicAdd(&sh_nsel, 1u);
        sel[s] = (uint32_t)candC[rsb][j] | ((uint32_t)rsb << 13);
      }
    }
  }
  __syncthreads();
  const uint32_t total = sh_nsel;   // == 2 * K_NEG

  const float xa0 = x_emb[r0 * 2], xa1 = x_emb[r0 * 2 + 1];
  const float xb0 = x_emb[r1 * 2], xb1 = x_emb[r1 * 2 + 1];
  const float qa = xa0 * xa0 + xa1 * xa1;
  const float qb = xb0 * xb0 + xb1 * xb1;
  const float2* temb2 = (const float2*)t_emb;

  // ---- phase 4: dense sweep over the 2032 selected entries ----
  float accA = 0.0f, accB = 0.0f;
  for (uint32_t j = tid; j < total; j += THREADS) {
    uint32_t e = sel[j];
    int col = e & 0x1FFFu;
    bool isB = (e & 0x2000u) != 0u;
    float2 t = temb2[col];
    float px = isB ? xb0 : xa0;
    float py = isB ? xb1 : xa1;
    float pq = isB ? qb : qa;
    float s = sim_fast(px, py, pq, t.x, t.y);
    float ez = hw_exp2(s * (INV_T * INV_LN2_F));
    if (isB) accB += ez; else accA += ez;
  }
#pragma unroll
  for (int off = 32; off > 0; off >>= 1) {
    accA += __shfl_down(accA, off);
    accB += __shfl_down(accB, off);
  }
  if (lane == 0) { shA[wv] = accA; shB[wv] = accB; }
  if (tid < 16) {
    int rowb = tid >> 3;
    int c = sh_pos[tid];
    float2 t = temb2[c];
    float px = rowb ? xb0 : xa0;
    float py = rowb ? xb1 : xa1;
    float pq = rowb ? qb : qa;
    sh_pp[tid] = sim_fast(px, py, pq, t.x, t.y);
  }
  __syncthreads();

  if (tid < 2) {
    float s = 0.0f;
#pragma unroll
    for (int w = 0; w < 16; ++w) s += tid ? shB[w] : shA[w];
    float ps = 0.0f;
#pragma unroll
    for (int p = 0; p < P_POS; ++p) ps += sh_pp[tid * P_POS + p];
    float pos = ps * (1.0f / P_POS);
    float zpos = pos * INV_T;
    float S = s + hw_exp2(zpos * INV_LN2_F) + N_PAD;
    float loss = logf(S) - zpos;
    int r = tid ? r1 : r0;
    if (row_loss) row_loss[r] = loss;
    else atomicAdd(out_atomic, loss * (1.0f / B_ROWS));
  }
}

__global__ __launch_bounds__(256) void cdr_reduce_kernel(
    const float* __restrict__ row_loss, float* __restrict__ out) {
  __shared__ float part[4];
  float s = 0.0f;
  for (int i = threadIdx.x; i < B_ROWS; i += 256) s += row_loss[i];
#pragma unroll
  for (int off = 32; off > 0; off >>= 1) s += __shfl_down(s, off);
  if ((threadIdx.x & 63) == 0) part[threadIdx.x >> 6] = s;
  __syncthreads();
  if (threadIdx.x == 0)
    out[0] = (part[0] + part[1] + part[2] + part[3]) * (1.0f / B_ROWS);
}

__global__ void cdr_zero_kernel(float* __restrict__ out) { out[0] = 0.0f; }

extern "C" void kernel_launch(void* const* d_in, const int* in_sizes, int n_in,
                              void* d_out, int out_size, void* d_ws, size_t ws_size,
                              hipStream_t stream) {
  const float* x_emb = (const float*)d_in[0];
  const float* t_emb = (const float*)d_in[1];
  const float* wf    = (const float*)d_in[2];
  const int*   pidx  = (const int*)d_in[3];
  float* out = (float*)d_out;

  uint32_t fk0 = 0u, fk1 = 1u;
  tf2x32(0u, 0u, fk0, fk1);

  const bool has_w75 = (ws_size >= (size_t)(NT_COLS + B_ROWS) * sizeof(float));
  const bool has_rl  = (ws_size >= (size_t)B_ROWS * sizeof(float));

  float* w75n = nullptr;
  float* row_loss = nullptr;
  if (has_w75) { w75n = (float*)d_ws; row_loss = (float*)d_ws + NT_COLS; }
  else if (has_rl) { row_loss = (float*)d_ws; }

  if (has_w75) {
    hipLaunchKernelGGL(prew_kernel, dim3(NT_COLS / 256), dim3(256), 0, stream,
                       wf, w75n);
  }
  if (!row_loss) {
    hipLaunchKernelGGL(cdr_zero_kernel, dim3(1), dim3(1), 0, stream, out);
  }
  hipLaunchKernelGGL(cdr_pair_kernel, dim3(HALF_B), dim3(THREADS), 0, stream,
                     x_emb, t_emb, w75n, wf, pidx, row_loss, out, fk0, fk1);
  if (row_loss) {
    hipLaunchKernelGGL(cdr_reduce_kernel, dim3(1), dim3(256), 0, stream,
                       row_loss, out);
  }
}